// Round 4
// baseline (387.319 us; speedup 1.0000x reference)
//
#include <hip/hip_runtime.h>
#include <math.h>

#define BATCH 4
#define DLAT 16
#define KCB 8192
#define HLAT 122
#define PIX (HLAT*HLAT)          // 14884
#define NLAT (BATCH*PIX)         // 59536
#define KCHUNKS 8
#define KC (KCB/KCHUNKS)         // 1024
#define TK 256                   // LDS subtile entries

// jax.nn.selu in fp32: scale * where(x>0, x, alpha*expm1(x))
__device__ __forceinline__ float selu_np(float x) {
    const float scale = 1.0507009873554805f, alpha = 1.6732632423543772f;
    if (x > 0.f) return __fmul_rn(scale, x);
    return __fmul_rn(scale, __fmul_rn(alpha, expm1f(x)));
}

// ---- fp32 VALID 3x3 conv, NCHW/OIHW, BLAS-like order: acc=0; fma over (c,p,q); +bias after ----
template<int CI, int CO, int HIN, int WIN, bool DOSELU>
__global__ void conv3x3_np(const float* __restrict__ in, const float* __restrict__ w,
                           const float* __restrict__ bias, float* __restrict__ out) {
    constexpr int HO = HIN - 2, WO = WIN - 2;
    int tid = blockIdx.x * blockDim.x + threadIdx.x;
    constexpr int total = BATCH * CO * HO * WO;
    if (tid >= total) return;
    int j = tid % WO; int t = tid / WO;
    int i = t % HO;   t /= HO;
    int o = t % CO;   int b = t / CO;
    float acc = 0.f;
    for (int c = 0; c < CI; ++c) {
        const float* ip = in + ((b * CI + c) * HIN + i) * WIN + j;
        const float* wp = w + ((o * CI + c) * 3) * 3;
        #pragma unroll
        for (int p = 0; p < 3; ++p)
            #pragma unroll
            for (int q = 0; q < 3; ++q)
                acc = __fmaf_rn(ip[p * WIN + q], wp[p * 3 + q], acc);
    }
    acc = __fadd_rn(acc, bias[o]);
    out[tid] = DOSELU ? selu_np(acc) : acc;
}

// ---- last encoder conv: (B,8,124,124) -> zf[(b*PIX + i*122 + j)*16 + o], no activation ----
__global__ void conv3x3_last_np(const float* __restrict__ in, const float* __restrict__ w,
                                const float* __restrict__ bias, float* __restrict__ zf) {
    constexpr int CI = 8, CO = 16, HIN = 124, WIN = 124, HO = 122, WO = 122;
    int tid = blockIdx.x * blockDim.x + threadIdx.x;
    constexpr int total = BATCH * CO * HO * WO;
    if (tid >= total) return;
    int j = tid % WO; int t = tid / WO;
    int i = t % HO;   t /= HO;
    int o = t % CO;   int b = t / CO;
    float acc = 0.f;
    for (int c = 0; c < CI; ++c) {
        const float* ip = in + ((b * CI + c) * HIN + i) * WIN + j;
        const float* wp = w + ((o * CI + c) * 3) * 3;
        #pragma unroll
        for (int p = 0; p < 3; ++p)
            #pragma unroll
            for (int q = 0; q < 3; ++q)
                acc = __fmaf_rn(ip[p * WIN + q], wp[p * 3 + q], acc);
    }
    acc = __fadd_rn(acc, bias[o]);
    zf[((size_t)(b * PIX) + i * WO + j) * DLAT + o] = acc;
}

// ---- numpy pairwise-16 sum of squares ----
__device__ __forceinline__ float pairwise16_sq(const float* v) {
    float a[16];
    #pragma unroll
    for (int d = 0; d < 16; ++d) a[d] = __fmul_rn(v[d], v[d]);
    float r0 = __fadd_rn(a[0], a[8]),  r1 = __fadd_rn(a[1], a[9]);
    float r2 = __fadd_rn(a[2], a[10]), r3 = __fadd_rn(a[3], a[11]);
    float r4 = __fadd_rn(a[4], a[12]), r5 = __fadd_rn(a[5], a[13]);
    float r6 = __fadd_rn(a[6], a[14]), r7 = __fadd_rn(a[7], a[15]);
    return __fadd_rn(__fadd_rn(__fadd_rn(r0, r1), __fadd_rn(r2, r3)),
                     __fadd_rn(__fadd_rn(r4, r5), __fadd_rn(r6, r7)));
}

__global__ void cnorm_np(const float* __restrict__ cb, float* __restrict__ cn) {
    int k = blockIdx.x * blockDim.x + threadIdx.x;
    if (k >= KCB) return;
    cn[k] = pairwise16_sq(cb + (size_t)k * DLAT);
}

// ---- VQ partial argmin, exact np-fp32 formula: d2 = fl(fl(A - 2G) + C) ----
__global__ void vq_partial_np(const float* __restrict__ zf, const float* __restrict__ cb,
                              const float* __restrict__ cn,
                              float* __restrict__ bestd, int* __restrict__ besti) {
    __shared__ float4 se4[TK * DLAT / 4];   // 16 KB
    __shared__ float sn[TK];                // 1 KB
    float* se = (float*)se4;
    int n = blockIdx.x * blockDim.x + threadIdx.x;
    int kbase = blockIdx.y * KC;
    bool active = n < NLAT;
    float zr[DLAT];
    float A = 0.f;
    if (active) {
        #pragma unroll
        for (int d = 0; d < DLAT; ++d) zr[d] = zf[(size_t)n * DLAT + d];
        A = pairwise16_sq(zr);
    }
    float bd = INFINITY; int bi = kbase;
    for (int t = 0; t < KC; t += TK) {
        __syncthreads();
        const float4* src = (const float4*)(cb + (size_t)(kbase + t) * DLAT);
        #pragma unroll
        for (int u = 0; u < (TK * DLAT / 4) / 256; ++u)
            se4[threadIdx.x + u * 256] = src[threadIdx.x + u * 256];
        if (threadIdx.x < TK) sn[threadIdx.x] = cn[kbase + t + threadIdx.x];
        __syncthreads();
        if (active) {
            for (int k = 0; k < TK; ++k) {
                const float* e = se + k * DLAT;
                float g = 0.f;
                #pragma unroll
                for (int d = 0; d < DLAT; ++d) g = __fmaf_rn(zr[d], e[d], g);
                float t1 = __fsub_rn(A, __fmul_rn(2.f, g));
                float d2 = __fadd_rn(t1, sn[k]);
                if (d2 < bd) { bd = d2; bi = kbase + t + k; }  // strict < => first occurrence
            }
        }
    }
    if (active) {
        bestd[(size_t)blockIdx.y * NLAT + n] = bd;
        besti[(size_t)blockIdx.y * NLAT + n] = bi;
    }
}

// ---- reduce over K-chunks (ascending => first-min) + gather zq + write idx ----
__global__ void vq_reduce_gather(const float* __restrict__ bestd, const int* __restrict__ besti,
                                 const float* __restrict__ cb,
                                 float* __restrict__ idx_out, float* __restrict__ zq) {
    int n = blockIdx.x * blockDim.x + threadIdx.x;
    if (n >= NLAT) return;
    float bd = INFINITY; int bi = 0;
    #pragma unroll
    for (int c = 0; c < KCHUNKS; ++c) {
        float d = bestd[(size_t)c * NLAT + n];
        int i = besti[(size_t)c * NLAT + n];
        if (d < bd) { bd = d; bi = i; }
    }
    idx_out[n] = (float)bi;
    int b = n / PIX, pix = n % PIX;
    const float* e = cb + (size_t)bi * DLAT;
    #pragma unroll
    for (int d = 0; d < DLAT; ++d) zq[((size_t)(b * DLAT + d)) * PIX + pix] = e[d];
}

// ---- fp32 transpose conv (stride1, k3, pad2), weights (CI,CO,3,3) ----
template<int CI, int CO, int HIN, int WIN, bool DOSELU>
__global__ void convt3x3(const float* __restrict__ in, const float* __restrict__ w,
                         const float* __restrict__ bias, float* __restrict__ out) {
    constexpr int HO = HIN + 2, WO = WIN + 2;
    int tid = blockIdx.x * blockDim.x + threadIdx.x;
    constexpr int total = BATCH * CO * HO * WO;
    if (tid >= total) return;
    int j = tid % WO; int t = tid / WO;
    int i = t % HO;   t /= HO;
    int o = t % CO;   int b = t / CO;
    float acc = bias[o];
    for (int c = 0; c < CI; ++c) {
        const float* ip = in + ((b * CI + c) * HIN) * WIN;
        const float* wp = w + ((c * CO + o) * 3) * 3;
        #pragma unroll
        for (int p = 0; p < 3; ++p) {
            int ii = i + p - 2;
            if (ii < 0 || ii >= HIN) continue;
            #pragma unroll
            for (int q = 0; q < 3; ++q) {
                int jj = j + q - 2;
                if (jj < 0 || jj >= WIN) continue;
                acc += ip[ii * WIN + jj] * wp[(2 - p) * 3 + (2 - q)];
            }
        }
    }
    const float scale = 1.0507009873554805f, alpha = 1.6732632423543772f;
    out[tid] = DOSELU ? (acc > 0.f ? scale * acc : scale * alpha * (expf(acc) - 1.f)) : acc;
}

extern "C" void kernel_launch(void* const* d_in, const int* in_sizes, int n_in,
                              void* d_out, int out_size, void* d_ws, size_t ws_size,
                              hipStream_t stream) {
    const float* x   = (const float*)d_in[0];
    const float* ew1 = (const float*)d_in[1];  const float* eb1 = (const float*)d_in[2];
    const float* ew2 = (const float*)d_in[3];  const float* eb2 = (const float*)d_in[4];
    const float* ew3 = (const float*)d_in[5];  const float* eb3 = (const float*)d_in[6];
    const float* dw1 = (const float*)d_in[7];  const float* db1 = (const float*)d_in[8];
    const float* dw2 = (const float*)d_in[9];  const float* db2 = (const float*)d_in[10];
    const float* dw3 = (const float*)d_in[11]; const float* db3 = (const float*)d_in[12];
    const float* cb  = (const float*)d_in[13];

    float* out_y   = (float*)d_out;                 // 196608
    float* out_idx = (float*)d_out + 196608;        // 59536 (as float)

    // ---- workspace (floats) ----
    float* ws = (float*)d_ws;
    float* zf  = ws;                         // 952576  [n][16], persists into VQ
    float* U   = zf + 952576;                // union region (1698624 floats)
    //   encoder phase:
    float* e1  = U;                          // 254016
    float* e2  = e1 + 254016;                // 492032
    //   decoder phase (after encoder done):
    float* fZq = U;                          // 952576
    float* fB  = fZq + 952576;               // 492032
    float* fA  = fB + 492032;                // 254016
    float* cn    = U + 1698624;              // 8192
    float* bestd = cn + 8192;                // 476288
    int*   besti = (int*)(bestd + (size_t)KCHUNKS * NLAT);  // 476288 ints

    const int TPB = 256;

    // encoder (fp32, np-order replica)
    conv3x3_np<3, 4, 128, 128, true ><<<(254016 + TPB - 1) / TPB, TPB, 0, stream>>>(x,  ew1, eb1, e1);
    conv3x3_np<4, 8, 126, 126, true ><<<(492032 + TPB - 1) / TPB, TPB, 0, stream>>>(e1, ew2, eb2, e2);
    conv3x3_last_np<<<(952576 + TPB - 1) / TPB, TPB, 0, stream>>>(e2, ew3, eb3, zf);

    // VQ (np-fp32 formula replica)
    cnorm_np<<<KCB / TPB, TPB, 0, stream>>>(cb, cn);
    dim3 vgrid((NLAT + TPB - 1) / TPB, KCHUNKS);
    vq_partial_np<<<vgrid, TPB, 0, stream>>>(zf, cb, cn, bestd, besti);
    vq_reduce_gather<<<(NLAT + TPB - 1) / TPB, TPB, 0, stream>>>(bestd, besti, cb, out_idx, fZq);

    // decoder (fp32)
    convt3x3<16, 8, 122, 122, true ><<<(492032 + TPB - 1) / TPB, TPB, 0, stream>>>(fZq, dw1, db1, fB);
    convt3x3<8, 4, 124, 124, true ><<<(254016 + TPB - 1) / TPB, TPB, 0, stream>>>(fB,  dw2, db2, fA);
    convt3x3<4, 3, 126, 126, false><<<(196608 + TPB - 1) / TPB, TPB, 0, stream>>>(fA,  dw3, db3, out_y);
}

// Round 5
// 344.216 us; speedup vs baseline: 1.1252x; 1.1252x over previous
//
#include <hip/hip_runtime.h>
#include <math.h>

#define BATCH 4
#define DLAT 16
#define KCB 8192
#define HLAT 122
#define PIX (HLAT*HLAT)          // 14884
#define NLAT (BATCH*PIX)         // 59536
#define KCHUNKS 16
#define KC (KCB/KCHUNKS)         // 512
#define TK 256                   // LDS subtile entries

// jax.nn.selu in fp32: scale * where(x>0, x, alpha*expm1(x))
__device__ __forceinline__ float selu_np(float x) {
    const float scale = 1.0507009873554805f, alpha = 1.6732632423543772f;
    if (x > 0.f) return __fmul_rn(scale, x);
    return __fmul_rn(scale, __fmul_rn(alpha, expm1f(x)));
}

// ---- fp32 VALID 3x3 conv, NCHW/OIHW, BLAS-like order: acc=0; fma over (c,p,q); +bias after ----
template<int CI, int CO, int HIN, int WIN, bool DOSELU>
__global__ void conv3x3_np(const float* __restrict__ in, const float* __restrict__ w,
                           const float* __restrict__ bias, float* __restrict__ out) {
    constexpr int HO = HIN - 2, WO = WIN - 2;
    int tid = blockIdx.x * blockDim.x + threadIdx.x;
    constexpr int total = BATCH * CO * HO * WO;
    if (tid >= total) return;
    int j = tid % WO; int t = tid / WO;
    int i = t % HO;   t /= HO;
    int o = t % CO;   int b = t / CO;
    float acc = 0.f;
    for (int c = 0; c < CI; ++c) {
        const float* ip = in + ((b * CI + c) * HIN + i) * WIN + j;
        const float* wp = w + ((o * CI + c) * 3) * 3;
        #pragma unroll
        for (int p = 0; p < 3; ++p)
            #pragma unroll
            for (int q = 0; q < 3; ++q)
                acc = __fmaf_rn(ip[p * WIN + q], wp[p * 3 + q], acc);
    }
    acc = __fadd_rn(acc, bias[o]);
    out[tid] = DOSELU ? selu_np(acc) : acc;
}

// ---- last encoder conv: (B,8,124,124) -> zf[(b*PIX + i*122 + j)*16 + o], no activation ----
__global__ void conv3x3_last_np(const float* __restrict__ in, const float* __restrict__ w,
                                const float* __restrict__ bias, float* __restrict__ zf) {
    constexpr int CI = 8, CO = 16, HIN = 124, WIN = 124, HO = 122, WO = 122;
    int tid = blockIdx.x * blockDim.x + threadIdx.x;
    constexpr int total = BATCH * CO * HO * WO;
    if (tid >= total) return;
    int j = tid % WO; int t = tid / WO;
    int i = t % HO;   t /= HO;
    int o = t % CO;   int b = t / CO;
    float acc = 0.f;
    for (int c = 0; c < CI; ++c) {
        const float* ip = in + ((b * CI + c) * HIN + i) * WIN + j;
        const float* wp = w + ((o * CI + c) * 3) * 3;
        #pragma unroll
        for (int p = 0; p < 3; ++p)
            #pragma unroll
            for (int q = 0; q < 3; ++q)
                acc = __fmaf_rn(ip[p * WIN + q], wp[p * 3 + q], acc);
    }
    acc = __fadd_rn(acc, bias[o]);
    zf[((size_t)(b * PIX) + i * WO + j) * DLAT + o] = acc;
}

// ---- numpy pairwise-16 sum of squares ----
__device__ __forceinline__ float pairwise16_sq(const float* v) {
    float a[16];
    #pragma unroll
    for (int d = 0; d < 16; ++d) a[d] = __fmul_rn(v[d], v[d]);
    float r0 = __fadd_rn(a[0], a[8]),  r1 = __fadd_rn(a[1], a[9]);
    float r2 = __fadd_rn(a[2], a[10]), r3 = __fadd_rn(a[3], a[11]);
    float r4 = __fadd_rn(a[4], a[12]), r5 = __fadd_rn(a[5], a[13]);
    float r6 = __fadd_rn(a[6], a[14]), r7 = __fadd_rn(a[7], a[15]);
    return __fadd_rn(__fadd_rn(__fadd_rn(r0, r1), __fadd_rn(r2, r3)),
                     __fadd_rn(__fadd_rn(r4, r5), __fadd_rn(r6, r7)));
}

__global__ void cnorm_np(const float* __restrict__ cb, float* __restrict__ cn) {
    int k = blockIdx.x * blockDim.x + threadIdx.x;
    if (k >= KCB) return;
    cn[k] = pairwise16_sq(cb + (size_t)k * DLAT);
}

// ---- VQ partial argmin, 4 latents/thread (q = batch), np-fp32 formula ----
// d2 = fl(fl(A - 2G) + C); fmaf(-2,g,A) == fsub(A, 2*g) exactly (2g exact).
__global__ __launch_bounds__(256, 4)
void vq_partial_np4(const float* __restrict__ zf, const float* __restrict__ cb,
                    const float* __restrict__ cn,
                    float* __restrict__ bestd, int* __restrict__ besti) {
    __shared__ float4 se4[TK * DLAT / 4];   // 16 KB
    __shared__ float sn[TK];                // 1 KB
    float* se = (float*)se4;
    int pix = blockIdx.x * blockDim.x + threadIdx.x;
    int kbase = blockIdx.y * KC;
    bool active = pix < PIX;
    float zr[4][DLAT];
    float A[4];
    if (active) {
        #pragma unroll
        for (int q = 0; q < 4; ++q) {
            const float4* zp = (const float4*)(zf + ((size_t)q * PIX + pix) * DLAT);
            float4 z0 = zp[0], z1 = zp[1], z2 = zp[2], z3 = zp[3];
            zr[q][0]=z0.x; zr[q][1]=z0.y; zr[q][2]=z0.z; zr[q][3]=z0.w;
            zr[q][4]=z1.x; zr[q][5]=z1.y; zr[q][6]=z1.z; zr[q][7]=z1.w;
            zr[q][8]=z2.x; zr[q][9]=z2.y; zr[q][10]=z2.z; zr[q][11]=z2.w;
            zr[q][12]=z3.x; zr[q][13]=z3.y; zr[q][14]=z3.z; zr[q][15]=z3.w;
            A[q] = pairwise16_sq(zr[q]);
        }
    }
    float bd[4] = {INFINITY, INFINITY, INFINITY, INFINITY};
    int bi[4] = {kbase, kbase, kbase, kbase};
    for (int t = 0; t < KC; t += TK) {
        __syncthreads();
        const float4* src = (const float4*)(cb + (size_t)(kbase + t) * DLAT);
        #pragma unroll
        for (int u = 0; u < (TK * DLAT / 4) / 256; ++u)
            se4[threadIdx.x + u * 256] = src[threadIdx.x + u * 256];
        sn[threadIdx.x] = cn[kbase + t + threadIdx.x];
        __syncthreads();
        if (active) {
            #pragma unroll 2
            for (int k = 0; k < TK; ++k) {
                const float4* e4 = (const float4*)(se + k * DLAT);
                float4 e0 = e4[0], e1 = e4[1], e2 = e4[2], e3 = e4[3];
                float c = sn[k];
                #pragma unroll
                for (int q = 0; q < 4; ++q) {
                    float g = 0.f;
                    g = __fmaf_rn(zr[q][0],  e0.x, g); g = __fmaf_rn(zr[q][1],  e0.y, g);
                    g = __fmaf_rn(zr[q][2],  e0.z, g); g = __fmaf_rn(zr[q][3],  e0.w, g);
                    g = __fmaf_rn(zr[q][4],  e1.x, g); g = __fmaf_rn(zr[q][5],  e1.y, g);
                    g = __fmaf_rn(zr[q][6],  e1.z, g); g = __fmaf_rn(zr[q][7],  e1.w, g);
                    g = __fmaf_rn(zr[q][8],  e2.x, g); g = __fmaf_rn(zr[q][9],  e2.y, g);
                    g = __fmaf_rn(zr[q][10], e2.z, g); g = __fmaf_rn(zr[q][11], e2.w, g);
                    g = __fmaf_rn(zr[q][12], e3.x, g); g = __fmaf_rn(zr[q][13], e3.y, g);
                    g = __fmaf_rn(zr[q][14], e3.z, g);
                    g = __fmaf_rn(zr[q][15], e3.w, g);
                    float d2 = __fadd_rn(__fmaf_rn(-2.f, g, A[q]), c);
                    if (d2 < bd[q]) { bd[q] = d2; bi[q] = kbase + t + k; }  // strict <
                }
            }
        }
    }
    if (active) {
        #pragma unroll
        for (int q = 0; q < 4; ++q) {
            bestd[(size_t)blockIdx.y * NLAT + q * PIX + pix] = bd[q];
            besti[(size_t)blockIdx.y * NLAT + q * PIX + pix] = bi[q];
        }
    }
}

// ---- reduce over K-chunks (ascending => first-min) + gather zq + write idx ----
__global__ void vq_reduce_gather(const float* __restrict__ bestd, const int* __restrict__ besti,
                                 const float* __restrict__ cb,
                                 float* __restrict__ idx_out, float* __restrict__ zq) {
    int n = blockIdx.x * blockDim.x + threadIdx.x;
    if (n >= NLAT) return;
    float bd = INFINITY; int bi = 0;
    #pragma unroll
    for (int c = 0; c < KCHUNKS; ++c) {
        float d = bestd[(size_t)c * NLAT + n];
        int i = besti[(size_t)c * NLAT + n];
        if (d < bd) { bd = d; bi = i; }
    }
    idx_out[n] = (float)bi;
    int b = n / PIX, pix = n % PIX;
    const float* e = cb + (size_t)bi * DLAT;
    #pragma unroll
    for (int d = 0; d < DLAT; ++d) zq[((size_t)(b * DLAT + d)) * PIX + pix] = e[d];
}

// ---- fp32 transpose conv (stride1, k3, pad2), weights (CI,CO,3,3) ----
template<int CI, int CO, int HIN, int WIN, bool DOSELU>
__global__ void convt3x3(const float* __restrict__ in, const float* __restrict__ w,
                         const float* __restrict__ bias, float* __restrict__ out) {
    constexpr int HO = HIN + 2, WO = WIN + 2;
    int tid = blockIdx.x * blockDim.x + threadIdx.x;
    constexpr int total = BATCH * CO * HO * WO;
    if (tid >= total) return;
    int j = tid % WO; int t = tid / WO;
    int i = t % HO;   t /= HO;
    int o = t % CO;   int b = t / CO;
    float acc = bias[o];
    for (int c = 0; c < CI; ++c) {
        const float* ip = in + ((b * CI + c) * HIN) * WIN;
        const float* wp = w + ((c * CO + o) * 3) * 3;
        #pragma unroll
        for (int p = 0; p < 3; ++p) {
            int ii = i + p - 2;
            if (ii < 0 || ii >= HIN) continue;
            #pragma unroll
            for (int q = 0; q < 3; ++q) {
                int jj = j + q - 2;
                if (jj < 0 || jj >= WIN) continue;
                acc += ip[ii * WIN + jj] * wp[(2 - p) * 3 + (2 - q)];
            }
        }
    }
    const float scale = 1.0507009873554805f, alpha = 1.6732632423543772f;
    out[tid] = DOSELU ? (acc > 0.f ? scale * acc : scale * alpha * (expf(acc) - 1.f)) : acc;
}

extern "C" void kernel_launch(void* const* d_in, const int* in_sizes, int n_in,
                              void* d_out, int out_size, void* d_ws, size_t ws_size,
                              hipStream_t stream) {
    const float* x   = (const float*)d_in[0];
    const float* ew1 = (const float*)d_in[1];  const float* eb1 = (const float*)d_in[2];
    const float* ew2 = (const float*)d_in[3];  const float* eb2 = (const float*)d_in[4];
    const float* ew3 = (const float*)d_in[5];  const float* eb3 = (const float*)d_in[6];
    const float* dw1 = (const float*)d_in[7];  const float* db1 = (const float*)d_in[8];
    const float* dw2 = (const float*)d_in[9];  const float* db2 = (const float*)d_in[10];
    const float* dw3 = (const float*)d_in[11]; const float* db3 = (const float*)d_in[12];
    const float* cb  = (const float*)d_in[13];

    float* out_y   = (float*)d_out;                 // 196608
    float* out_idx = (float*)d_out + 196608;        // 59536 (as float)

    // ---- workspace (floats), aggressive aliasing; total = 2,865,920 f = 10.9 MiB ----
    float* ws = (float*)d_ws;
    float* zf    = ws;                    // [0 .. 952576)   zf (enc out); later fZq (reduce out)
    float* fZq   = ws;                    //   alias: zf dead when reduce writes fZq
    float* bestd = ws + 952576;           // [952576 .. 1905152)
    int*   besti = (int*)(ws + 1905152);  // [1905152 .. 2857728)
    float* cn    = ws + 2857728;          // [2857728 .. 2865920)
    //  encoder temps alias bestd/besti region (dead before VQ writes them):
    float* e1 = ws + 952576;              // 254016
    float* e2 = ws + 1206592;             // 492032  (ends 1698624 < 2857728)
    //  decoder temps alias bestd region (bestd/besti dead after reduce):
    float* fB = ws + 952576;              // 492032
    float* fA = ws + 1444608;             // 254016  (ends 1698624)

    const int TPB = 256;

    // encoder (fp32, np-order replica)
    conv3x3_np<3, 4, 128, 128, true ><<<(254016 + TPB - 1) / TPB, TPB, 0, stream>>>(x,  ew1, eb1, e1);
    conv3x3_np<4, 8, 126, 126, true ><<<(492032 + TPB - 1) / TPB, TPB, 0, stream>>>(e1, ew2, eb2, e2);
    conv3x3_last_np<<<(952576 + TPB - 1) / TPB, TPB, 0, stream>>>(e2, ew3, eb3, zf);

    // VQ (np-fp32 formula replica, 4 latents/thread)
    cnorm_np<<<KCB / TPB, TPB, 0, stream>>>(cb, cn);
    dim3 vgrid((PIX + TPB - 1) / TPB, KCHUNKS);   // (59, 16)
    vq_partial_np4<<<vgrid, TPB, 0, stream>>>(zf, cb, cn, bestd, besti);
    vq_reduce_gather<<<(NLAT + TPB - 1) / TPB, TPB, 0, stream>>>(bestd, besti, cb, out_idx, fZq);

    // decoder (fp32)
    convt3x3<16, 8, 122, 122, true ><<<(492032 + TPB - 1) / TPB, TPB, 0, stream>>>(fZq, dw1, db1, fB);
    convt3x3<8, 4, 124, 124, true ><<<(254016 + TPB - 1) / TPB, TPB, 0, stream>>>(fB,  dw2, db2, fA);
    convt3x3<4, 3, 126, 126, false><<<(196608 + TPB - 1) / TPB, TPB, 0, stream>>>(fA,  dw3, db3, out_y);
}

// Round 6
// 315.986 us; speedup vs baseline: 1.2257x; 1.0893x over previous
//
#include <hip/hip_runtime.h>
#include <math.h>

#define BATCH 4
#define DLAT 16
#define KCB 8192
#define HLAT 122
#define PIX (HLAT*HLAT)          // 14884
#define NLAT (BATCH*PIX)         // 59536
#define KCHUNKS 32
#define KC (KCB/KCHUNKS)         // 256

// jax.nn.selu in fp32: scale * where(x>0, x, alpha*expm1(x))
__device__ __forceinline__ float selu_np(float x) {
    const float scale = 1.0507009873554805f, alpha = 1.6732632423543772f;
    if (x > 0.f) return __fmul_rn(scale, x);
    return __fmul_rn(scale, __fmul_rn(alpha, expm1f(x)));
}

// ---- fp32 VALID 3x3 conv, NCHW/OIHW, BLAS-like order: acc=0; fma over (c,p,q); +bias after ----
template<int CI, int CO, int HIN, int WIN, bool DOSELU>
__global__ void conv3x3_np(const float* __restrict__ in, const float* __restrict__ w,
                           const float* __restrict__ bias, float* __restrict__ out) {
    constexpr int HO = HIN - 2, WO = WIN - 2;
    int tid = blockIdx.x * blockDim.x + threadIdx.x;
    constexpr int total = BATCH * CO * HO * WO;
    if (tid >= total) return;
    int j = tid % WO; int t = tid / WO;
    int i = t % HO;   t /= HO;
    int o = t % CO;   int b = t / CO;
    float acc = 0.f;
    for (int c = 0; c < CI; ++c) {
        const float* ip = in + ((b * CI + c) * HIN + i) * WIN + j;
        const float* wp = w + ((o * CI + c) * 3) * 3;
        #pragma unroll
        for (int p = 0; p < 3; ++p)
            #pragma unroll
            for (int q = 0; q < 3; ++q)
                acc = __fmaf_rn(ip[p * WIN + q], wp[p * 3 + q], acc);
    }
    acc = __fadd_rn(acc, bias[o]);
    out[tid] = DOSELU ? selu_np(acc) : acc;
}

// ---- last encoder conv: (B,8,124,124) -> zf[(b*PIX + i*122 + j)*16 + o], no activation ----
__global__ void conv3x3_last_np(const float* __restrict__ in, const float* __restrict__ w,
                                const float* __restrict__ bias, float* __restrict__ zf) {
    constexpr int CI = 8, CO = 16, HIN = 124, WIN = 124, HO = 122, WO = 122;
    int tid = blockIdx.x * blockDim.x + threadIdx.x;
    constexpr int total = BATCH * CO * HO * WO;
    if (tid >= total) return;
    int j = tid % WO; int t = tid / WO;
    int i = t % HO;   t /= HO;
    int o = t % CO;   int b = t / CO;
    float acc = 0.f;
    for (int c = 0; c < CI; ++c) {
        const float* ip = in + ((b * CI + c) * HIN + i) * WIN + j;
        const float* wp = w + ((o * CI + c) * 3) * 3;
        #pragma unroll
        for (int p = 0; p < 3; ++p)
            #pragma unroll
            for (int q = 0; q < 3; ++q)
                acc = __fmaf_rn(ip[p * WIN + q], wp[p * 3 + q], acc);
    }
    acc = __fadd_rn(acc, bias[o]);
    zf[((size_t)(b * PIX) + i * WO + j) * DLAT + o] = acc;
}

// ---- numpy pairwise-16 sum of squares ----
__device__ __forceinline__ float pairwise16_sq(const float* v) {
    float a[16];
    #pragma unroll
    for (int d = 0; d < 16; ++d) a[d] = __fmul_rn(v[d], v[d]);
    float r0 = __fadd_rn(a[0], a[8]),  r1 = __fadd_rn(a[1], a[9]);
    float r2 = __fadd_rn(a[2], a[10]), r3 = __fadd_rn(a[3], a[11]);
    float r4 = __fadd_rn(a[4], a[12]), r5 = __fadd_rn(a[5], a[13]);
    float r6 = __fadd_rn(a[6], a[14]), r7 = __fadd_rn(a[7], a[15]);
    return __fadd_rn(__fadd_rn(__fadd_rn(r0, r1), __fadd_rn(r2, r3)),
                     __fadd_rn(__fadd_rn(r4, r5), __fadd_rn(r6, r7)));
}

__global__ void cnorm_np(const float* __restrict__ cb, float* __restrict__ cn) {
    int k = blockIdx.x * blockDim.x + threadIdx.x;
    if (k >= KCB) return;
    cn[k] = pairwise16_sq(cb + (size_t)k * DLAT);
}

// ---- VQ partial argmin, 4 latents/thread, codebook via wave-uniform (scalar) loads ----
// d2 = fl(fl(A - 2G) + C); fmaf(-2,g,A) == fsub(A, 2*g) exactly (2g exact).
__global__ __launch_bounds__(256, 4)
void vq_partial_np4s(const float* __restrict__ zf, const float* __restrict__ cb,
                     const float* __restrict__ cn,
                     float* __restrict__ bestd, int* __restrict__ besti) {
    int pix = blockIdx.x * blockDim.x + threadIdx.x;
    int kbase = blockIdx.y * KC;
    bool active = pix < PIX;
    int pcl = active ? pix : (PIX - 1);     // clamp: inactive lanes duplicate last pixel
    float zr[4][DLAT];
    float A[4];
    #pragma unroll
    for (int q = 0; q < 4; ++q) {
        const float4* zp = (const float4*)(zf + ((size_t)q * PIX + pcl) * DLAT);
        float4 z0 = zp[0], z1 = zp[1], z2 = zp[2], z3 = zp[3];
        zr[q][0]=z0.x; zr[q][1]=z0.y; zr[q][2]=z0.z; zr[q][3]=z0.w;
        zr[q][4]=z1.x; zr[q][5]=z1.y; zr[q][6]=z1.z; zr[q][7]=z1.w;
        zr[q][8]=z2.x; zr[q][9]=z2.y; zr[q][10]=z2.z; zr[q][11]=z2.w;
        zr[q][12]=z3.x; zr[q][13]=z3.y; zr[q][14]=z3.z; zr[q][15]=z3.w;
        A[q] = pairwise16_sq(zr[q]);
    }
    float bd[4] = {INFINITY, INFINITY, INFINITY, INFINITY};
    int bi[4] = {kbase, kbase, kbase, kbase};
    const float* cbc = cb + (size_t)kbase * DLAT;   // uniform base
    const float* cnc = cn + kbase;
    #pragma unroll 2
    for (int k = 0; k < KC; ++k) {
        const float* e = cbc + (size_t)k * DLAT;    // uniform address -> s_load
        float c = cnc[k];                           // uniform -> s_load
        float g[4] = {0.f, 0.f, 0.f, 0.f};
        #pragma unroll
        for (int d = 0; d < DLAT; ++d) {
            float ed = e[d];
            g[0] = __fmaf_rn(zr[0][d], ed, g[0]);
            g[1] = __fmaf_rn(zr[1][d], ed, g[1]);
            g[2] = __fmaf_rn(zr[2][d], ed, g[2]);
            g[3] = __fmaf_rn(zr[3][d], ed, g[3]);
        }
        #pragma unroll
        for (int q = 0; q < 4; ++q) {
            float d2 = __fadd_rn(__fmaf_rn(-2.f, g[q], A[q]), c);
            if (d2 < bd[q]) { bd[q] = d2; bi[q] = kbase + k; }   // strict < => first occurrence
        }
    }
    if (active) {
        #pragma unroll
        for (int q = 0; q < 4; ++q) {
            bestd[(size_t)blockIdx.y * NLAT + q * PIX + pix] = bd[q];
            besti[(size_t)blockIdx.y * NLAT + q * PIX + pix] = bi[q];
        }
    }
}

// ---- reduce over K-chunks (ascending => first-min) + gather zq + write idx ----
__global__ void vq_reduce_gather(const float* __restrict__ bestd, const int* __restrict__ besti,
                                 const float* __restrict__ cb,
                                 float* __restrict__ idx_out, float* __restrict__ zq) {
    int n = blockIdx.x * blockDim.x + threadIdx.x;
    if (n >= NLAT) return;
    float bd = INFINITY; int bi = 0;
    #pragma unroll
    for (int c = 0; c < KCHUNKS; ++c) {
        float d = bestd[(size_t)c * NLAT + n];
        int i = besti[(size_t)c * NLAT + n];
        if (d < bd) { bd = d; bi = i; }
    }
    idx_out[n] = (float)bi;
    int b = n / PIX, pix = n % PIX;
    const float* e = cb + (size_t)bi * DLAT;
    #pragma unroll
    for (int d = 0; d < DLAT; ++d) zq[((size_t)(b * DLAT + d)) * PIX + pix] = e[d];
}

// ---- fp32 transpose conv (stride1, k3, pad2), weights (CI,CO,3,3) ----
template<int CI, int CO, int HIN, int WIN, bool DOSELU>
__global__ void convt3x3(const float* __restrict__ in, const float* __restrict__ w,
                         const float* __restrict__ bias, float* __restrict__ out) {
    constexpr int HO = HIN + 2, WO = WIN + 2;
    int tid = blockIdx.x * blockDim.x + threadIdx.x;
    constexpr int total = BATCH * CO * HO * WO;
    if (tid >= total) return;
    int j = tid % WO; int t = tid / WO;
    int i = t % HO;   t /= HO;
    int o = t % CO;   int b = t / CO;
    float acc = bias[o];
    for (int c = 0; c < CI; ++c) {
        const float* ip = in + ((b * CI + c) * HIN) * WIN;
        const float* wp = w + ((c * CO + o) * 3) * 3;
        #pragma unroll
        for (int p = 0; p < 3; ++p) {
            int ii = i + p - 2;
            if (ii < 0 || ii >= HIN) continue;
            #pragma unroll
            for (int q = 0; q < 3; ++q) {
                int jj = j + q - 2;
                if (jj < 0 || jj >= WIN) continue;
                acc += ip[ii * WIN + jj] * wp[(2 - p) * 3 + (2 - q)];
            }
        }
    }
    const float scale = 1.0507009873554805f, alpha = 1.6732632423543772f;
    out[tid] = DOSELU ? (acc > 0.f ? scale * acc : scale * alpha * (expf(acc) - 1.f)) : acc;
}

extern "C" void kernel_launch(void* const* d_in, const int* in_sizes, int n_in,
                              void* d_out, int out_size, void* d_ws, size_t ws_size,
                              hipStream_t stream) {
    const float* x   = (const float*)d_in[0];
    const float* ew1 = (const float*)d_in[1];  const float* eb1 = (const float*)d_in[2];
    const float* ew2 = (const float*)d_in[3];  const float* eb2 = (const float*)d_in[4];
    const float* ew3 = (const float*)d_in[5];  const float* eb3 = (const float*)d_in[6];
    const float* dw1 = (const float*)d_in[7];  const float* db1 = (const float*)d_in[8];
    const float* dw2 = (const float*)d_in[9];  const float* db2 = (const float*)d_in[10];
    const float* dw3 = (const float*)d_in[11]; const float* db3 = (const float*)d_in[12];
    const float* cb  = (const float*)d_in[13];

    float* out_y   = (float*)d_out;                 // 196608
    float* out_idx = (float*)d_out + 196608;        // 59536 (as float)

    // ---- workspace (floats); total 4,771,072 f = 18.2 MiB (< 19.3 MiB proven in R3) ----
    float* ws = (float*)d_ws;
    float* zf    = ws;                    // [0 .. 952576)  enc out; later aliased by fZq
    float* fZq   = ws;
    float* bestd = ws + 952576;           // [952576 .. 2857728)   32*NLAT
    int*   besti = (int*)(ws + 2857728);  // [2857728 .. 4762880)
    float* cn    = ws + 4762880;          // [4762880 .. 4771072)
    //  encoder temps alias bestd region (dead before VQ writes):
    float* e1 = ws + 952576;              // 254016
    float* e2 = ws + 1206592;             // 492032 (ends 1698624 < 2857728)
    //  decoder temps alias bestd region (bestd/besti dead after reduce):
    float* fB = ws + 952576;              // 492032
    float* fA = ws + 1444608;             // 254016 (ends 1698624)

    const int TPB = 256;

    // encoder (fp32, np-order replica)
    conv3x3_np<3, 4, 128, 128, true ><<<(254016 + TPB - 1) / TPB, TPB, 0, stream>>>(x,  ew1, eb1, e1);
    conv3x3_np<4, 8, 126, 126, true ><<<(492032 + TPB - 1) / TPB, TPB, 0, stream>>>(e1, ew2, eb2, e2);
    conv3x3_last_np<<<(952576 + TPB - 1) / TPB, TPB, 0, stream>>>(e2, ew3, eb3, zf);

    // VQ (np-fp32 formula replica; scalar-path codebook)
    cnorm_np<<<KCB / TPB, TPB, 0, stream>>>(cb, cn);
    dim3 vgrid((PIX + TPB - 1) / TPB, KCHUNKS);   // (59, 32) = 1888 blocks
    vq_partial_np4s<<<vgrid, TPB, 0, stream>>>(zf, cb, cn, bestd, besti);
    vq_reduce_gather<<<(NLAT + TPB - 1) / TPB, TPB, 0, stream>>>(bestd, besti, cb, out_idx, fZq);

    // decoder (fp32)
    convt3x3<16, 8, 122, 122, true ><<<(492032 + TPB - 1) / TPB, TPB, 0, stream>>>(fZq, dw1, db1, fB);
    convt3x3<8, 4, 124, 124, true ><<<(254016 + TPB - 1) / TPB, TPB, 0, stream>>>(fB,  dw2, db2, fA);
    convt3x3<4, 3, 126, 126, false><<<(196608 + TPB - 1) / TPB, TPB, 0, stream>>>(fA,  dw3, db3, out_y);
}